// Round 1
// baseline (407.857 us; speedup 1.0000x reference)
//
#include <hip/hip_runtime.h>

// Problem constants
#define DD   768      // appearance dim
#define NH   8        // heads
#define DKh  96       // key/geo dim
#define NROW 2048     // B*K
#define NCOL 2304     // 3*NH*DKh

typedef __attribute__((ext_vector_type(8))) short short8;   // 8 bf16
typedef __attribute__((ext_vector_type(4))) float f32x4;

__device__ __forceinline__ unsigned short f2bf(float x) {
    union { float f; unsigned int u; } v; v.f = x;
    unsigned int r = v.u + 0x7FFFu + ((v.u >> 16) & 1u);   // RNE
    return (unsigned short)(r >> 16);
}

// ---------------- 1. f_a fp32 -> bf16 ----------------
__global__ __launch_bounds__(256) void k_cvt_a(const float* __restrict__ fa,
                                               unsigned short* __restrict__ abf) {
    int idx = blockIdx.x * 256 + threadIdx.x;          // 393216 float4 exactly
    float4 v = ((const float4*)fa)[idx];
    ushort4 o;
    o.x = f2bf(v.x); o.y = f2bf(v.y); o.z = f2bf(v.z); o.w = f2bf(v.w);
    ((ushort4*)abf)[idx] = o;
}

// ---------------- 2. W[K|Q|V] -> bf16, transposed to [col][d] ----------------
// input  WX_w: [8][768][96] fp32 ; output wbf[c*768+d], c = p*768 + h*96 + e
__global__ __launch_bounds__(256) void k_cvt_w(const float* __restrict__ wk,
                                               const float* __restrict__ wq,
                                               const float* __restrict__ wv,
                                               unsigned short* __restrict__ wbf) {
    __shared__ float ls[64 * 97];                      // pad 97: conflict-free
    int pid = blockIdx.x / 12;                         // 0..23 = (p,h)
    int db  = blockIdx.x % 12;                         // d-block of 64
    int p = pid >> 3, h = pid & 7;
    const float* src = (p == 0 ? wk : p == 1 ? wq : wv) + h * DD * DKh + db * 64 * DKh;
    int t = threadIdx.x;
#pragma unroll
    for (int i = 0; i < 24; ++i) {                     // 64 rows x 96, coalesced
        int f = t + 256 * i;
        int dl = f / 96, e = f - dl * 96;
        ls[dl * 97 + e] = src[f];
    }
    __syncthreads();
    unsigned short* dst = wbf + (p * 768 + h * 96) * DD + db * 64;
#pragma unroll
    for (int i = 0; i < 24; ++i) {
        int f = t + 256 * i;
        int e = f >> 6, dl = f & 63;
        dst[e * DD + dl] = f2bf(ls[dl * 97 + e]);
    }
}

// ---------------- 3. projections: C[2048x2304] = A x W, MFMA bf16 ----------------
// outputs: kb[b,h,m,e] bf16 ; qb[b,h,n,e] bf16 (pre-scaled 1/sqrt(96)) ; vt[b,h,e,m] bf16
__global__ __launch_bounds__(256) void k_proj(const unsigned short* __restrict__ abf,
                                              const unsigned short* __restrict__ wbf,
                                              const float* __restrict__ wkb,
                                              const float* __restrict__ wqb,
                                              const float* __restrict__ wvb,
                                              unsigned short* __restrict__ kb,
                                              unsigned short* __restrict__ qb,
                                              unsigned short* __restrict__ vt) {
    int w = threadIdx.x >> 6, lane = threadIdx.x & 63;
    int lrow = lane & 15, quad = lane >> 4;
    int rt = blockIdx.x / 9, cg = blockIdx.x % 9;
    int r0 = rt * 16;
    int c0 = cg * 256 + w * 64;                        // wave: 16 rows x 64 cols
    f32x4 z = {0.f, 0.f, 0.f, 0.f};
    f32x4 acc[4] = {z, z, z, z};
    for (int kk = 0; kk < DD; kk += 32) {
        short8 a = *(const short8*)(abf + (r0 + lrow) * DD + kk + quad * 8);
#pragma unroll
        for (int tt = 0; tt < 4; ++tt) {
            short8 b = *(const short8*)(wbf + (c0 + tt * 16 + lrow) * DD + kk + quad * 8);
            acc[tt] = __builtin_amdgcn_mfma_f32_16x16x32_bf16(a, b, acc[tt], 0, 0, 0);
        }
    }
    int rbase = r0 + quad * 4;
    int b_ = rbase >> 8, mbase = rbase & 255;
#pragma unroll
    for (int tt = 0; tt < 4; ++tt) {
        int cc = c0 + tt * 16 + lrow;                  // p,h uniform per tile
        int p = cc / 768, rm = cc - p * 768;
        int h = rm / 96,  e = rm - h * 96;
        float bias = (p == 0 ? wkb : p == 1 ? wqb : wvb)[h * 96 + e];
        if (p == 2) {                                  // V transposed: [e][m], m packed x4
            ushort4 v4;
            v4.x = f2bf(acc[tt][0] + bias);
            v4.y = f2bf(acc[tt][1] + bias);
            v4.z = f2bf(acc[tt][2] + bias);
            v4.w = f2bf(acc[tt][3] + bias);
            *(ushort4*)(vt + ((b_ * 8 + h) * 96 + e) * 256 + mbase) = v4;
        } else {
            float sc = (p == 1) ? 0.10206207261596577f : 1.0f;   // fold 1/sqrt(96) into Q
            unsigned short* dst = (p == 0 ? kb : qb) + ((b_ * 8 + h) * 256 + mbase) * 96 + e;
#pragma unroll
            for (int r = 0; r < 4; ++r)
                dst[r * 96] = f2bf((acc[tt][r] + bias) * sc);
        }
    }
}

// ---------------- 4. geometric bias: L[b,h,m,n] = log(max(pe.WG+b, 1e-6)) ----------------
__global__ __launch_bounds__(256) void k_wg(const float* __restrict__ pe,
                                            const float* __restrict__ wgw,
                                            const float* __restrict__ wgb,
                                            float* __restrict__ L) {
    __shared__ float ps[64 * 97];                      // 64 pe rows, pad 97
    int bi = blockIdx.x;
    int b = bi >> 10, rem = bi & 1023;
    int m = rem >> 2, nb = rem & 3;
    int n0 = nb * 64;
    int t = threadIdx.x;
    const float* src = pe + ((b * 256 + m) * 256 + n0) * 96;   // 24 KB contiguous
#pragma unroll
    for (int i = 0; i < 24; ++i) {
        int f = t + 256 * i;
        int r = f / 96, e = f - r * 96;
        ps[r * 97 + e] = src[f];
    }
    __syncthreads();
    int wq_ = __builtin_amdgcn_readfirstlane((int)(threadIdx.x >> 6));  // head-pair, SGPR
    const float* w0 = wgw + (2 * wq_) * 96;            // uniform -> s_load
    const float* w1 = w0 + 96;
    float acc0 = wgb[2 * wq_], acc1 = wgb[2 * wq_ + 1];
    int n = t & 63;
    const float* row = ps + n * 97;                    // bank = (n+g)%32, conflict-free
#pragma unroll
    for (int g = 0; g < 96; ++g) {
        float pv = row[g];
        acc0 = fmaf(pv, w0[g], acc0);
        acc1 = fmaf(pv, w1[g], acc1);
    }
    float l0 = __logf(fmaxf(acc0, 1e-6f));             // relu+clip collapse to max(.,1e-6)
    float l1 = __logf(fmaxf(acc1, 1e-6f));
    int h0 = 2 * wq_;
    L[((b * 8 + h0) * 256 + m) * 256 + n0 + n] = l0;
    L[((b * 8 + h0 + 1) * 256 + m) * 256 + n0 + n] = l1;
}

// ---------------- 5. scores: L[m][n] += sum_e K[m,e] * Qscaled[n,e] ----------------
__global__ __launch_bounds__(256) void k_score(const unsigned short* __restrict__ kb,
                                               const unsigned short* __restrict__ qb,
                                               float* __restrict__ L) {
    int w = threadIdx.x >> 6, lane = threadIdx.x & 63;
    int lrow = lane & 15, quad = lane >> 4;
    int tid = blockIdx.x * 4 + w;
    int bh = tid >> 8, rem = tid & 255;
    int mt = rem >> 4, nt = rem & 15;
    int m0 = mt * 16, n0 = nt * 16;
    f32x4 acc = {0.f, 0.f, 0.f, 0.f};
    const unsigned short* ka = kb + (bh * 256 + m0 + lrow) * 96 + quad * 8;  // A rows=m
    const unsigned short* qa = qb + (bh * 256 + n0 + lrow) * 96 + quad * 8;  // B cols=n
#pragma unroll
    for (int kk = 0; kk < 96; kk += 32) {
        short8 a = *(const short8*)(ka + kk);
        short8 b = *(const short8*)(qa + kk);
        acc = __builtin_amdgcn_mfma_f32_16x16x32_bf16(a, b, acc, 0, 0, 0);
    }
    float* lp = L + (bh * 256 + m0 + quad * 4) * 256 + n0 + lrow;   // D[m][n] coalesced
#pragma unroll
    for (int r = 0; r < 4; ++r)
        lp[r * 256] += acc[r];
}

// ---------------- 6. softmax over m (per b,h,n) -> Pt[b,h,n,m] bf16, normalized ----------------
__global__ __launch_bounds__(256) void k_softmax(const float* __restrict__ L,
                                                 unsigned short* __restrict__ pt) {
    __shared__ float Ps[32 * 264];                     // 32 n-rows x 256 m, pad 264
    __shared__ float inv_s[32];
    int bh = blockIdx.x >> 3, nbk = blockIdx.x & 7;
    int n0 = nbk * 32;
    int t = threadIdx.x;
    int nl = t >> 3, j = t & 7;                        // 8 threads per n, same wave
    const float* base = L + bh * 65536 + n0 + nl;
    float mx = -3.4e38f;
    for (int m0 = 0; m0 < 256; m0 += 8)
        mx = fmaxf(mx, base[(m0 + j) * 256]);
    mx = fmaxf(mx, __shfl_xor(mx, 1));
    mx = fmaxf(mx, __shfl_xor(mx, 2));
    mx = fmaxf(mx, __shfl_xor(mx, 4));
    float sum = 0.f;
    for (int m0 = 0; m0 < 256; m0 += 8) {
        float v = base[(m0 + j) * 256];
        float e = __expf(v - mx);
        sum += e;
        Ps[nl * 264 + m0 + j] = e;                     // bank-conflict-free
    }
    sum += __shfl_xor(sum, 1);
    sum += __shfl_xor(sum, 2);
    sum += __shfl_xor(sum, 4);
    if (j == 0) inv_s[nl] = 1.0f / sum;
    __syncthreads();
    unsigned short* dst = pt + (bh * 256 + n0) * 256;  // transposed coalesced writeout
#pragma unroll 4
    for (int i = 0; i < 32; ++i)
        dst[i * 256 + t] = f2bf(Ps[i * 264 + t] * inv_s[i]);
}

// ---------------- 7. out[b,n,h*96+e] = sum_m Pt[n,m] * V[m,e] + f_a ----------------
__global__ __launch_bounds__(256) void k_attnv(const unsigned short* __restrict__ pt,
                                               const unsigned short* __restrict__ vt,
                                               const float* __restrict__ fa,
                                               float* __restrict__ out) {
    int w = threadIdx.x >> 6, lane = threadIdx.x & 63;
    int lrow = lane & 15, quad = lane >> 4;
    int tid = blockIdx.x * 4 + w;
    int bh = tid / 96, rem = tid - bh * 96;
    int nt = rem / 6, et = rem - nt * 6;
    int n0 = nt * 16, e0 = et * 16;
    int b_ = bh >> 3, h = bh & 7;
    f32x4 acc = {0.f, 0.f, 0.f, 0.f};
    const unsigned short* pa = pt + (bh * 256 + n0 + lrow) * 256 + quad * 8;  // A[n][m]
    const unsigned short* va = vt + (bh * 96 + e0 + lrow) * 256 + quad * 8;   // B[m][e] from [e][m]
#pragma unroll
    for (int mk = 0; mk < 256; mk += 32) {
        short8 a = *(const short8*)(pa + mk);
        short8 b = *(const short8*)(va + mk);
        acc = __builtin_amdgcn_mfma_f32_16x16x32_bf16(a, b, acc, 0, 0, 0);
    }
    int idx = (b_ * 256 + n0 + quad * 4) * 768 + h * 96 + e0 + lrow;
#pragma unroll
    for (int r = 0; r < 4; ++r)
        out[idx + r * 768] = acc[r] + fa[idx + r * 768];
}

extern "C" void kernel_launch(void* const* d_in, const int* in_sizes, int n_in,
                              void* d_out, int out_size, void* d_ws, size_t ws_size,
                              hipStream_t stream) {
    const float* fa  = (const float*)d_in[0];
    const float* pe  = (const float*)d_in[1];
    const float* wgw = (const float*)d_in[2];
    const float* wgb = (const float*)d_in[3];
    const float* wkw = (const float*)d_in[4];
    const float* wkb = (const float*)d_in[5];
    const float* wqw = (const float*)d_in[6];
    const float* wqb = (const float*)d_in[7];
    const float* wvw = (const float*)d_in[8];
    const float* wvb = (const float*)d_in[9];
    float* out = (float*)d_out;
    char* ws = (char*)d_ws;
    // workspace layout (41.3 MB total)
    unsigned short* abf = (unsigned short*)(ws);              // 2048*768 bf16   = 3,145,728 B
    unsigned short* wbf = (unsigned short*)(ws + 3145728);    // 2304*768 bf16   = 3,538,944 B
    unsigned short* kb  = (unsigned short*)(ws + 6684672);    // 64*256*96 bf16  = 3,145,728 B
    unsigned short* qb  = (unsigned short*)(ws + 9830400);    // 64*256*96 bf16  = 3,145,728 B
    unsigned short* vt  = (unsigned short*)(ws + 12976128);   // 64*96*256 bf16  = 3,145,728 B
    float*          L   = (float*)(ws + 16121856);            // 64*256*256 f32  = 16,777,216 B
    unsigned short* pt  = (unsigned short*)(ws + 32899072);   // 64*256*256 bf16 = 8,388,608 B

    k_cvt_a  <<<1536, 256, 0, stream>>>(fa, abf);
    k_cvt_w  <<< 288, 256, 0, stream>>>(wkw, wqw, wvw, wbf);
    k_proj   <<<1152, 256, 0, stream>>>(abf, wbf, wkb, wqb, wvb, kb, qb, vt);
    k_wg     <<<8192, 256, 0, stream>>>(pe, wgw, wgb, L);
    k_score  <<<4096, 256, 0, stream>>>(kb, qb, L);
    k_softmax<<< 512, 256, 0, stream>>>(L, pt);
    k_attnv  <<<1536, 256, 0, stream>>>(pt, vt, fa, out);
}